// Round 1
// baseline (29651.367 us; speedup 1.0000x reference)
//
#include <hip/hip_runtime.h>
#include <math.h>

#define BB 32
#define LL 512
#define EE 512
#define HH 1024
#define VV 32000
#define TT 64
#define G4 4096
#define NPRED 33024  // VV + HH

__device__ __forceinline__ float fast_tanh(float x){
  float ax = fabsf(x);
  float e = __expf(ax + ax);
  float r = 1.0f - 2.0f/(e + 1.0f);
  return copysignf(r, x);
}

// ---------------- init ----------------
__global__ void k_init(float* __restrict__ outp, float* __restrict__ a0t,
                       float* __restrict__ a1t, float* __restrict__ c0,
                       float* __restrict__ c1, float* __restrict__ q,
                       const float* __restrict__ bad, int* __restrict__ token,
                       const int* __restrict__ trg, const int* __restrict__ sosp,
                       float* __restrict__ predout){
  int idx = blockIdx.x*256 + threadIdx.x;
  if (idx < 1024000){ int b = idx / VV; int v = idx % VV;
    outp[(size_t)b*TT*VV + v] = 0.f; return; }
  idx -= 1024000;
  if (idx < 49152){ a0t[idx]=0.f; return; } idx -= 49152;
  if (idx < 65536){ a1t[idx]=0.f; return; } idx -= 65536;
  if (idx < 32768){ c0[idx]=0.f; return; } idx -= 32768;
  if (idx < 32768){ c1[idx]=0.f; return; } idx -= 32768;
  if (idx < 32768){ q[idx] = bad[idx & (HH-1)]; return; } idx -= 32768;
  if (idx < 32){ token[idx] = trg[idx*TT]; return; } idx -= 32;
  if (idx < 32){ predout[idx*TT] = (float)(*sosp); return; }
}

// ---------------- generic transpose: dst[c*ds + r] = src[r*ss + c] ----------
__global__ void k_transpose(const float* __restrict__ src, int ss,
                            float* __restrict__ dst, int ds, int R, int C){
  __shared__ float tile[32][33];
  int c0 = blockIdx.x*32, r0 = blockIdx.y*32;
  int tx = threadIdx.x, ty = threadIdx.y;  // (32,8)
  #pragma unroll
  for (int i=0;i<32;i+=8)
    tile[ty+i][tx] = src[(size_t)(r0+ty+i)*ss + c0+tx];
  __syncthreads();
  #pragma unroll
  for (int i=0;i<32;i+=8)
    dst[(size_t)(c0+ty+i)*ds + r0+tx] = tile[tx][ty+i];
}

// ---------------- precompute GEMM: C[m][n] = sum_k AT[k][m]*WT[k][n] (+bias)
// grid (256 mtiles, N/128), block 256. lane=m (coalesced A), W via uniform loads.
__global__ __launch_bounds__(256) void k_pregemm(const float* __restrict__ AT,
    const float* __restrict__ WT, const float* __restrict__ bias,
    float* __restrict__ Cout, int N, int Kdim){
  int mt = blockIdx.x, ntg = blockIdx.y;
  int w = threadIdx.x >> 6, lane = threadIdx.x & 63;
  int m = mt*64 + lane;
  int nbase = ntg*128 + w*32;
  float acc[32];
  #pragma unroll
  for (int j=0;j<32;j++) acc[j]=0.f;
  const float* ap = AT + m;
  const float* wp = WT + nbase;
  for (int k=0;k<Kdim;k++){
    float a = ap[(size_t)k*16384];
    const float4* w4 = (const float4*)(wp + (size_t)k*N);
    #pragma unroll
    for (int j4=0;j4<8;j4++){
      float4 wv = w4[j4];
      acc[j4*4+0] = fmaf(a, wv.x, acc[j4*4+0]);
      acc[j4*4+1] = fmaf(a, wv.y, acc[j4*4+1]);
      acc[j4*4+2] = fmaf(a, wv.z, acc[j4*4+2]);
      acc[j4*4+3] = fmaf(a, wv.w, acc[j4*4+3]);
    }
  }
  __shared__ float tile[64][133];
  #pragma unroll
  for (int j=0;j<32;j++){
    float bv = bias ? bias[nbase+j] : 0.f;
    tile[lane][w*32+j] = acc[j] + bv;
  }
  __syncthreads();
  #pragma unroll
  for (int i=0;i<32;i++){
    int flat = i*256 + threadIdx.x;
    int mm = flat >> 7, nn = flat & 127;
    Cout[(size_t)(mt*64+mm)*N + ntg*128 + nn] = tile[mm][nn];
  }
}

// ---------------- attention scores (+ argmax of previous step's pred) -------
__global__ __launch_bounds__(256) void k_score(const float* __restrict__ ep,
    const float* __restrict__ qbuf, const float* __restrict__ vatt,
    float* __restrict__ scores, const float* __restrict__ argv,
    const int* __restrict__ argi, int* __restrict__ token,
    float* __restrict__ predout, int t){
  int b = blockIdx.x, lt = blockIdx.y;
  int w = threadIdx.x >> 6, lane = threadIdx.x & 63;
  __shared__ float qs[HH], vs[HH];
  for (int i=threadIdx.x; i<HH; i+=256){ qs[i]=qbuf[b*HH+i]; vs[i]=vatt[i]; }
  __syncthreads();
  if (lt==0 && t>1 && w==0){
    float bv = -INFINITY; int bi = 0x7fffffff;
    for (int j=lane; j<500; j+=64){
      float v = argv[j*32 + b]; int ix = argi[j*32 + b];
      if (v > bv || (v==bv && ix < bi)){ bv=v; bi=ix; }
    }
    #pragma unroll
    for (int d=32; d>0; d>>=1){
      float ov = __shfl_down(bv, d); int oi = __shfl_down(bi, d);
      if (ov > bv || (ov==bv && oi < bi)){ bv=ov; bi=oi; }
    }
    if (lane==0){ token[b]=bi; predout[b*TT + (t-1)] = (float)bi; }
  }
  for (int i=0;i<16;i++){
    int l = lt*64 + w*16 + i;
    const float4* row = (const float4*)(ep + ((size_t)(b*LL + l))*HH);
    float acc = 0.f;
    #pragma unroll
    for (int c=0;c<4;c++){
      float4 xv = row[c*64 + lane];
      float4 qv = ((const float4*)qs)[c*64 + lane];
      float4 vv = ((const float4*)vs)[c*64 + lane];
      acc += fast_tanh(xv.x+qv.x)*vv.x;
      acc += fast_tanh(xv.y+qv.y)*vv.y;
      acc += fast_tanh(xv.z+qv.z)*vv.z;
      acc += fast_tanh(xv.w+qv.w)*vv.w;
    }
    #pragma unroll
    for (int d=32; d>0; d>>=1) acc += __shfl_down(acc, d);
    if (lane==0) scores[b*LL + l] = acc;
  }
}

// ---------------- softmax + x = alpha@encW2 + emb@W1T + b_in ----------------
__global__ __launch_bounds__(256) void k_attnx(const float* __restrict__ scores,
    const float* __restrict__ encW2, const float* __restrict__ emb,
    const int* __restrict__ token, const float* __restrict__ W1T,
    const float* __restrict__ b_in, float* __restrict__ A0T){
  int b = blockIdx.x, eh = blockIdx.y;
  __shared__ float alpha[LL];
  __shared__ float embs[EE];
  __shared__ float red[8];
  int tx = threadIdx.x;
  float s0 = scores[b*LL + tx], s1 = scores[b*LL + 256 + tx];
  float mx = fmaxf(s0, s1);
  #pragma unroll
  for (int d=32; d>0; d>>=1) mx = fmaxf(mx, __shfl_down(mx, d));
  if ((tx&63)==0) red[tx>>6] = mx;
  __syncthreads();
  mx = fmaxf(fmaxf(red[0],red[1]), fmaxf(red[2],red[3]));
  float e0 = __expf(s0-mx), e1 = __expf(s1-mx);
  float sm = e0+e1;
  #pragma unroll
  for (int d=32; d>0; d>>=1) sm += __shfl_down(sm, d);
  if ((tx&63)==0) red[4+(tx>>6)] = sm;
  __syncthreads();
  sm = red[4]+red[5]+red[6]+red[7];
  float inv = 1.0f/sm;
  alpha[tx] = e0*inv; alpha[tx+256] = e1*inv;
  int tok = token[b];
  embs[tx] = emb[(size_t)tok*EE + tx];
  embs[tx+256] = emb[(size_t)tok*EE + 256 + tx];
  __syncthreads();
  int e = eh*256 + tx;
  float acc = b_in[e];
  const float* cw = encW2 + (size_t)b*LL*EE + e;
  for (int l=0;l<LL;l++) acc = fmaf(alpha[l], cw[(size_t)l*EE], acc);
  const float* wp = W1T + e;
  for (int j=0;j<EE;j++) acc = fmaf(embs[j], wp[(size_t)j*EE], acc);
  A0T[e*32 + b] = acc;
}

// ---------------- LSTM gates GEMM (K-split 16, partials) --------------------
__global__ __launch_bounds__(256) void k_lstm_gemm(const float* __restrict__ AT,
    const float* __restrict__ WT, float* __restrict__ partial, int Kdim){
  int nt = blockIdx.x & 15, ks = blockIdx.x >> 4;
  int w = threadIdx.x >> 6, lane = threadIdx.x & 63;
  int n = nt*256 + w*64 + lane;
  int kslice = Kdim >> 4;
  int k0 = ks*kslice, k1 = k0 + kslice;
  float acc[32];
  #pragma unroll
  for (int j=0;j<32;j++) acc[j]=0.f;
  for (int k=k0;k<k1;k++){
    float wv = WT[(size_t)k*G4 + n];
    const float4* a4 = (const float4*)(AT + k*32);
    #pragma unroll
    for (int j4=0;j4<8;j4++){
      float4 av = a4[j4];
      acc[j4*4+0]=fmaf(av.x,wv,acc[j4*4+0]);
      acc[j4*4+1]=fmaf(av.y,wv,acc[j4*4+1]);
      acc[j4*4+2]=fmaf(av.z,wv,acc[j4*4+2]);
      acc[j4*4+3]=fmaf(av.w,wv,acc[j4*4+3]);
    }
  }
  float* p = partial + ((size_t)ks*32)*G4 + n;
  #pragma unroll
  for (int b=0;b<32;b++) p[(size_t)b*G4] = acc[b];
}

// ---------------- cell update ----------------
__global__ __launch_bounds__(256) void k_cell(const float* __restrict__ partial,
    const float* __restrict__ b_ih, const float* __restrict__ b_hh,
    float* __restrict__ c, float* __restrict__ hdst1, float* __restrict__ hdst2){
  int idx = blockIdx.x*256 + threadIdx.x;
  int b = idx >> 10, h = idx & 1023;
  const float* pb = partial + (size_t)b*G4;
  float gi = b_ih[h]      + b_hh[h];
  float gf = b_ih[1024+h] + b_hh[1024+h];
  float gg = b_ih[2048+h] + b_hh[2048+h];
  float go = b_ih[3072+h] + b_hh[3072+h];
  #pragma unroll
  for (int ks=0; ks<16; ks++){
    const float* pp = pb + (size_t)ks*32*G4;
    gi += pp[h]; gf += pp[1024+h]; gg += pp[2048+h]; go += pp[3072+h];
  }
  float cv = c[idx];
  float si = 1.f/(1.f+expf(-gi));
  float sf = 1.f/(1.f+expf(-gf));
  float so = 1.f/(1.f+expf(-go));
  float tg = tanhf(gg);
  float c2 = sf*cv + si*tg;
  float h2 = so*tanhf(c2);
  c[idx] = c2;
  hdst1[h*32 + b] = h2;
  if (hdst2) hdst2[h*32 + b] = h2;
}

// ---------------- pred GEMM (W_fc ++ W_att_dec rows) + argmax partials ------
__global__ __launch_bounds__(256) void k_pred(const float* __restrict__ h1T,
    const float* __restrict__ WcatPT, const float* __restrict__ b_fc,
    const float* __restrict__ bad, float* __restrict__ outp,
    float* __restrict__ qbuf, float* __restrict__ argv, int* __restrict__ argi,
    int t){
  int w = threadIdx.x >> 6, lane = threadIdx.x & 63;
  int n = blockIdx.x*64 + lane;
  float acc[32];
  #pragma unroll
  for (int j=0;j<32;j++) acc[j]=0.f;
  int k0 = w*256;
  const float* wp = WcatPT + (size_t)k0*NPRED + n;
  const float4* ap = (const float4*)(h1T + k0*32);
  for (int k=0;k<256;k++){
    float wv = wp[(size_t)k*NPRED];
    const float4* a4 = ap + k*8;
    #pragma unroll
    for (int j4=0;j4<8;j4++){
      float4 av = a4[j4];
      acc[j4*4+0]=fmaf(av.x,wv,acc[j4*4+0]);
      acc[j4*4+1]=fmaf(av.y,wv,acc[j4*4+1]);
      acc[j4*4+2]=fmaf(av.z,wv,acc[j4*4+2]);
      acc[j4*4+3]=fmaf(av.w,wv,acc[j4*4+3]);
    }
  }
  __shared__ float comb[3*64*36];
  if (w>0){
    float* dst = comb + ((w-1)*64 + lane)*36;
    #pragma unroll
    for (int b=0;b<32;b+=4)
      *(float4*)(dst+b) = make_float4(acc[b],acc[b+1],acc[b+2],acc[b+3]);
  }
  __syncthreads();
  if (w==0){
    #pragma unroll
    for (int ww=0;ww<3;ww++){
      const float* src = comb + (ww*64 + lane)*36;
      #pragma unroll
      for (int b=0;b<32;b+=4){
        float4 v4 = *(const float4*)(src+b);
        acc[b]+=v4.x; acc[b+1]+=v4.y; acc[b+2]+=v4.z; acc[b+3]+=v4.w;
      }
    }
    if (n < VV){
      float bias = b_fc[n];
      #pragma unroll
      for (int b=0;b<32;b++) acc[b] += bias;
      #pragma unroll
      for (int b=0;b<32;b++) outp[(size_t)(b*TT + t)*VV + n] = acc[b];
      for (int b=0;b<32;b++){
        float v = acc[b]; int ix = n;
        #pragma unroll
        for (int d=32; d>0; d>>=1){
          float ov = __shfl_down(v, d); int oi = __shfl_down(ix, d);
          if (ov > v || (ov==v && oi < ix)){ v=ov; ix=oi; }
        }
        if (lane==0){ argv[blockIdx.x*32 + b]=v; argi[blockIdx.x*32 + b]=ix; }
      }
    } else {
      int j = n - VV;
      float bias = bad[j];
      #pragma unroll
      for (int b=0;b<32;b++) qbuf[b*HH + j] = acc[b] + bias;
    }
  }
}

// ---------------- final argmax (step 63) ----------------
__global__ void k_argfinal(const float* __restrict__ argv,
                           const int* __restrict__ argi,
                           float* __restrict__ predout){
  int b = threadIdx.x >> 3, j = threadIdx.x & 7;
  float bv = -INFINITY; int bi = 0x7fffffff;
  for (int p=j; p<500; p+=8){
    float v = argv[p*32+b]; int ix = argi[p*32+b];
    if (v>bv || (v==bv && ix<bi)){ bv=v; bi=ix; }
  }
  #pragma unroll
  for (int d=4; d>0; d>>=1){
    float ov = __shfl_down(bv, d); int oi = __shfl_down(bi, d);
    if (ov>bv || (ov==bv && oi<bi)){ bv=ov; bi=oi; }
  }
  if (j==0) predout[b*TT + 63] = (float)bi;
}

extern "C" void kernel_launch(void* const* d_in, const int* in_sizes, int n_in,
                              void* d_out, int out_size, void* d_ws, size_t ws_size,
                              hipStream_t stream){
  const float* enc_output=(const float*)d_in[0];
  const int*   trg       =(const int*)d_in[1];
  const float* emb       =(const float*)d_in[2];
  const float* W_att_enc =(const float*)d_in[3];
  const float* b_att_enc =(const float*)d_in[4];
  const float* W_att_dec =(const float*)d_in[5];
  const float* b_att_dec =(const float*)d_in[6];
  const float* v_att     =(const float*)d_in[7];
  const float* W_in      =(const float*)d_in[8];
  const float* b_in      =(const float*)d_in[9];
  const float* W_ih0     =(const float*)d_in[10];
  const float* W_hh0     =(const float*)d_in[11];
  const float* b_ih0     =(const float*)d_in[12];
  const float* b_hh0     =(const float*)d_in[13];
  const float* W_ih1     =(const float*)d_in[14];
  const float* W_hh1     =(const float*)d_in[15];
  const float* b_ih1     =(const float*)d_in[16];
  const float* b_hh1     =(const float*)d_in[17];
  const float* W_fc      =(const float*)d_in[18];
  const float* b_fc      =(const float*)d_in[19];
  const int*   sosp      =(const int*)d_in[23];

  float* out = (float*)d_out;
  float* predout = out + (size_t)BB*TT*VV;
  float* ws = (float*)d_ws;

  float* WcatPT = ws;                      // [1024][33024]
  float* Wcat0T = ws + 33816576;           // [1536][4096]
  float* Wcat1T = ws + 40108032;           // [2048][4096]
  float* W1T    = ws + 48496640;           // [512][512]
  float* WinCtxT= ws + 48758784;           // [1024][512]
  float* WattET = ws + 49283072;           // [1024][1024]
  float* encT   = ws + 50331648;           // [1024][16384]
  float* ep     = ws + 67108864;           // [16384][1024]
  float* encW2  = ws + 83886080;           // [16384][512]
  float* part0  = ws + 92274688;           // [16][32][4096]
  float* part1  = ws + 94371840;
  float* A0T    = ws + 96468992;           // [1536][32]
  float* A1T    = ws + 96518144;           // [2048][32]
  float* c0     = ws + 96583680;
  float* c1     = ws + 96616448;
  float* q      = ws + 96649216;           // [32][1024]
  float* scores = ws + 96681984;           // [32][512]
  float* argv   = ws + 96698368;           // [500][32]
  int*   argi   = (int*)(ws + 96714368);   // [500][32]
  int*   token  = (int*)(ws + 96730368);   // [32]

  k_init<<<dim3(4833), dim3(256), 0, stream>>>(out, A0T, A1T, c0, c1, q,
      b_att_dec, token, trg, sosp, predout);

  auto TR=[&](const float* src,int ss,float* dst,int ds,int R,int C){
    k_transpose<<<dim3(C/32, R/32), dim3(32,8), 0, stream>>>(src, ss, dst, ds, R, C);
  };
  TR(W_fc, 1024, WcatPT, NPRED, VV, 1024);
  TR(W_att_dec, 1024, WcatPT + VV, NPRED, 1024, 1024);
  TR(W_ih0, 512, Wcat0T, G4, G4, 512);
  TR(W_hh0, 1024, Wcat0T + (size_t)512*G4, G4, G4, 1024);
  TR(W_ih1, 1024, Wcat1T, G4, G4, 1024);
  TR(W_hh1, 1024, Wcat1T + (size_t)1024*G4, G4, G4, 1024);
  TR(W_in, 1536, W1T, 512, 512, 512);
  TR(W_in + 512, 1536, WinCtxT, 512, 512, 1024);
  TR(W_att_enc, 1024, WattET, 1024, 1024, 1024);
  TR(enc_output, 1024, encT, 16384, 16384, 1024);

  k_pregemm<<<dim3(256,8), dim3(256), 0, stream>>>(encT, WattET, b_att_enc, ep, 1024, 1024);
  k_pregemm<<<dim3(256,4), dim3(256), 0, stream>>>(encT, WinCtxT, nullptr, encW2, 512, 1024);

  for (int t=1; t<TT; t++){
    k_score<<<dim3(32,8), dim3(256), 0, stream>>>(ep, q, v_att, scores,
        argv, argi, token, predout, t);
    k_attnx<<<dim3(32,2), dim3(256), 0, stream>>>(scores, encW2, emb, token,
        W1T, b_in, A0T);
    k_lstm_gemm<<<dim3(256), dim3(256), 0, stream>>>(A0T, Wcat0T, part0, 1536);
    k_cell<<<dim3(128), dim3(256), 0, stream>>>(part0, b_ih0, b_hh0, c0,
        A0T + (size_t)512*32, A1T);
    k_lstm_gemm<<<dim3(256), dim3(256), 0, stream>>>(A1T, Wcat1T, part1, 2048);
    k_cell<<<dim3(128), dim3(256), 0, stream>>>(part1, b_ih1, b_hh1, c1,
        A1T + (size_t)1024*32, nullptr);
    k_pred<<<dim3(516), dim3(256), 0, stream>>>(A1T + (size_t)1024*32, WcatPT,
        b_fc, b_att_dec, out, q, argv, argi, t);
  }
  k_argfinal<<<dim3(1), dim3(256), 0, stream>>>(argv, argi, predout);
}

// Round 2
// 25000.990 us; speedup vs baseline: 1.1860x; 1.1860x over previous
//
#include <hip/hip_runtime.h>
#include <math.h>

#define BB 32
#define LL 512
#define EE 512
#define HH 1024
#define VV 32000
#define TT 64
#define G4 4096
#define NPRED 33024  // VV + HH

__device__ __forceinline__ float fast_tanh(float x){
  float ax = fabsf(x);
  float e = __expf(ax + ax);
  float r = 1.0f - 2.0f/(e + 1.0f);
  return copysignf(r, x);
}

// ---------------- init ----------------
__global__ void k_init(float* __restrict__ outp, float* __restrict__ a0t,
                       float* __restrict__ a1t, float* __restrict__ c0,
                       float* __restrict__ c1, float* __restrict__ q,
                       const float* __restrict__ bad, int* __restrict__ token,
                       const int* __restrict__ trg, const int* __restrict__ sosp,
                       float* __restrict__ predout){
  int idx = blockIdx.x*256 + threadIdx.x;
  if (idx < 1024000){ int b = idx / VV; int v = idx % VV;
    outp[(size_t)b*TT*VV + v] = 0.f; return; }
  idx -= 1024000;
  if (idx < 49152){ a0t[idx]=0.f; return; } idx -= 49152;
  if (idx < 65536){ a1t[idx]=0.f; return; } idx -= 65536;
  if (idx < 32768){ c0[idx]=0.f; return; } idx -= 32768;
  if (idx < 32768){ c1[idx]=0.f; return; } idx -= 32768;
  if (idx < 32768){ q[idx] = bad[idx & (HH-1)]; return; } idx -= 32768;
  if (idx < 32){ token[idx] = trg[idx*TT]; return; } idx -= 32;
  if (idx < 32){ predout[idx*TT] = (float)(*sosp); return; }
}

// ---------------- generic transpose: dst[c*ds + r] = src[r*ss + c] ----------
__global__ void k_transpose(const float* __restrict__ src, int ss,
                            float* __restrict__ dst, int ds, int R, int C){
  __shared__ float tile[32][33];
  int c0 = blockIdx.x*32, r0 = blockIdx.y*32;
  int tx = threadIdx.x, ty = threadIdx.y;  // (32,8)
  #pragma unroll
  for (int i=0;i<32;i+=8)
    tile[ty+i][tx] = src[(size_t)(r0+ty+i)*ss + c0+tx];
  __syncthreads();
  #pragma unroll
  for (int i=0;i<32;i+=8)
    dst[(size_t)(c0+ty+i)*ds + r0+tx] = tile[tx][ty+i];
}

// ---------------- precompute GEMM: C[m][n] = sum_k AT[k][m]*WT[k][n] (+bias)
__global__ __launch_bounds__(256) void k_pregemm(const float* __restrict__ AT,
    const float* __restrict__ WT, const float* __restrict__ bias,
    float* __restrict__ Cout, int N, int Kdim){
  int mt = blockIdx.x, ntg = blockIdx.y;
  int w = threadIdx.x >> 6, lane = threadIdx.x & 63;
  int m = mt*64 + lane;
  int nbase = ntg*128 + w*32;
  float acc[32];
  #pragma unroll
  for (int j=0;j<32;j++) acc[j]=0.f;
  const float* ap = AT + m;
  const float* wp = WT + nbase;
  for (int k=0;k<Kdim;k++){
    float a = ap[(size_t)k*16384];
    const float4* w4 = (const float4*)(wp + (size_t)k*N);
    #pragma unroll
    for (int j4=0;j4<8;j4++){
      float4 wv = w4[j4];
      acc[j4*4+0] = fmaf(a, wv.x, acc[j4*4+0]);
      acc[j4*4+1] = fmaf(a, wv.y, acc[j4*4+1]);
      acc[j4*4+2] = fmaf(a, wv.z, acc[j4*4+2]);
      acc[j4*4+3] = fmaf(a, wv.w, acc[j4*4+3]);
    }
  }
  __shared__ float tile[64][133];
  #pragma unroll
  for (int j=0;j<32;j++){
    float bv = bias ? bias[nbase+j] : 0.f;
    tile[lane][w*32+j] = acc[j] + bv;
  }
  __syncthreads();
  #pragma unroll
  for (int i=0;i<32;i++){
    int flat = i*256 + threadIdx.x;
    int mm = flat >> 7, nn = flat & 127;
    Cout[(size_t)(mt*64+mm)*N + ntg*128 + nn] = tile[mm][nn];
  }
}

// ---------------- attention scores + q-combine + argmax of prev pred --------
// grid (32 b, 16 lt), block 256 (4 waves x 8 l each = 32 l per block)
__global__ __launch_bounds__(256) void k_score(const float* __restrict__ ep,
    const float* __restrict__ partP, const float* __restrict__ bad,
    const float* __restrict__ vatt, float* __restrict__ scores,
    const float* __restrict__ argv, const int* __restrict__ argi,
    int* __restrict__ token, float* __restrict__ predout, int t){
  int b = blockIdx.x, lt = blockIdx.y;
  int w = threadIdx.x >> 6, lane = threadIdx.x & 63;
  __shared__ float qs[HH], vs[HH];
  for (int i=threadIdx.x; i<HH; i+=256){
    float qv = bad[i];
    if (t > 1){
      qv += partP[(size_t)b*NPRED + VV + i]
          + partP[(size_t)(32+b)*NPRED + VV + i];
    }
    qs[i] = qv;
    vs[i] = vatt[i];
  }
  __syncthreads();
  if (lt==0 && t>1 && w==0){
    float bv = -INFINITY; int bi = 0x7fffffff;
    for (int j=lane; j<500; j+=64){
      float v = argv[j*32 + b]; int ix = argi[j*32 + b];
      if (v > bv || (v==bv && ix < bi)){ bv=v; bi=ix; }
    }
    #pragma unroll
    for (int d=32; d>0; d>>=1){
      float ov = __shfl_down(bv, d); int oi = __shfl_down(bi, d);
      if (ov > bv || (ov==bv && oi < bi)){ bv=ov; bi=oi; }
    }
    if (lane==0){ token[b]=bi; predout[b*TT + (t-1)] = (float)bi; }
  }
  #pragma unroll
  for (int i=0;i<8;i++){
    int l = lt*32 + w*8 + i;
    const float4* row = (const float4*)(ep + ((size_t)(b*LL + l))*HH);
    float acc = 0.f;
    #pragma unroll
    for (int c=0;c<4;c++){
      float4 xv = row[c*64 + lane];
      float4 qv = ((const float4*)qs)[c*64 + lane];
      float4 vv = ((const float4*)vs)[c*64 + lane];
      acc += fast_tanh(xv.x+qv.x)*vv.x;
      acc += fast_tanh(xv.y+qv.y)*vv.y;
      acc += fast_tanh(xv.z+qv.z)*vv.z;
      acc += fast_tanh(xv.w+qv.w)*vv.w;
    }
    #pragma unroll
    for (int d=32; d>0; d>>=1) acc += __shfl_down(acc, d);
    if (lane==0) scores[b*LL + l] = acc;
  }
}

// ---------------- softmax + x = alpha@encW2 + emb@W1T + b_in ----------------
// grid (32 b, 8 etiles of 64), block 256 = 4 waves; waves split the l/j loops.
__global__ __launch_bounds__(256) void k_attnx(const float* __restrict__ scores,
    const float* __restrict__ encW2, const float* __restrict__ emb,
    const int* __restrict__ token, const float* __restrict__ W1T,
    const float* __restrict__ b_in, float* __restrict__ A0T){
  int b = blockIdx.x, et = blockIdx.y;
  int tx = threadIdx.x;
  int w = tx >> 6, lane = tx & 63;
  __shared__ float alpha[LL];
  __shared__ float embs[EE];
  __shared__ float red[8];
  __shared__ float comb[4][64];
  float s0 = scores[b*LL + tx], s1 = scores[b*LL + 256 + tx];
  float mx = fmaxf(s0, s1);
  #pragma unroll
  for (int d=32; d>0; d>>=1) mx = fmaxf(mx, __shfl_down(mx, d));
  if ((tx&63)==0) red[tx>>6] = mx;
  __syncthreads();
  mx = fmaxf(fmaxf(red[0],red[1]), fmaxf(red[2],red[3]));
  float e0 = __expf(s0-mx), e1 = __expf(s1-mx);
  float sm = e0+e1;
  #pragma unroll
  for (int d=32; d>0; d>>=1) sm += __shfl_down(sm, d);
  if ((tx&63)==0) red[4+(tx>>6)] = sm;
  __syncthreads();
  sm = red[4]+red[5]+red[6]+red[7];
  float inv = 1.0f/sm;
  alpha[tx] = e0*inv; alpha[tx+256] = e1*inv;
  int tok = token[b];
  embs[tx] = emb[(size_t)tok*EE + tx];
  embs[tx+256] = emb[(size_t)tok*EE + 256 + tx];
  __syncthreads();
  int e = et*64 + lane;
  float acc = 0.f;
  const float* cw = encW2 + (size_t)b*LL*EE + (size_t)w*128*EE + e;
  #pragma unroll 4
  for (int l=0;l<128;l++) acc = fmaf(alpha[w*128+l], cw[(size_t)l*EE], acc);
  const float* wp = W1T + (size_t)w*128*EE + e;
  #pragma unroll 4
  for (int j=0;j<128;j++) acc = fmaf(embs[w*128+j], wp[(size_t)j*EE], acc);
  comb[w][lane] = acc;
  __syncthreads();
  if (w==0){
    float r = comb[0][lane]+comb[1][lane]+comb[2][lane]+comb[3][lane] + b_in[e];
    A0T[e*32 + b] = r;
  }
}

// ---------------- generic small-M GEMM with split-K partials ----------------
// partial[ks][b][n] = sum_{k in slice} A[k][b] * W[k][n]
// A layout [K][32]; W layout [K][N]. block 256 = 4 waves; wave w -> b in [8w,8w+8)
// lane covers 4 consecutive n; block covers 256 n. grid (N/256, ksplit).
__global__ __launch_bounds__(256) void k_gemm_smallM(const float* __restrict__ AT,
    const float* __restrict__ WT, float* __restrict__ partial,
    int N, int kslice){
  int nt = blockIdx.x, ks = blockIdx.y;
  int w = threadIdx.x >> 6, lane = threadIdx.x & 63;
  int n0 = nt*256 + lane*4;
  int b0 = w*8;
  int k0 = ks*kslice;
  float acc[8][4];
  #pragma unroll
  for (int i=0;i<8;i++)
    #pragma unroll
    for (int j=0;j<4;j++) acc[i][j]=0.f;
  const float* wp = WT + (size_t)k0*N + n0;
  const float* ap = AT + (size_t)k0*32 + b0;
  #pragma unroll 4
  for (int k=0;k<kslice;k++){
    float4 wv = *(const float4*)(wp);
    float4 a0 = *(const float4*)(ap);
    float4 a1 = *(const float4*)(ap+4);
    wp += N; ap += 32;
    acc[0][0]=fmaf(a0.x,wv.x,acc[0][0]); acc[0][1]=fmaf(a0.x,wv.y,acc[0][1]);
    acc[0][2]=fmaf(a0.x,wv.z,acc[0][2]); acc[0][3]=fmaf(a0.x,wv.w,acc[0][3]);
    acc[1][0]=fmaf(a0.y,wv.x,acc[1][0]); acc[1][1]=fmaf(a0.y,wv.y,acc[1][1]);
    acc[1][2]=fmaf(a0.y,wv.z,acc[1][2]); acc[1][3]=fmaf(a0.y,wv.w,acc[1][3]);
    acc[2][0]=fmaf(a0.z,wv.x,acc[2][0]); acc[2][1]=fmaf(a0.z,wv.y,acc[2][1]);
    acc[2][2]=fmaf(a0.z,wv.z,acc[2][2]); acc[2][3]=fmaf(a0.z,wv.w,acc[2][3]);
    acc[3][0]=fmaf(a0.w,wv.x,acc[3][0]); acc[3][1]=fmaf(a0.w,wv.y,acc[3][1]);
    acc[3][2]=fmaf(a0.w,wv.z,acc[3][2]); acc[3][3]=fmaf(a0.w,wv.w,acc[3][3]);
    acc[4][0]=fmaf(a1.x,wv.x,acc[4][0]); acc[4][1]=fmaf(a1.x,wv.y,acc[4][1]);
    acc[4][2]=fmaf(a1.x,wv.z,acc[4][2]); acc[4][3]=fmaf(a1.x,wv.w,acc[4][3]);
    acc[5][0]=fmaf(a1.y,wv.x,acc[5][0]); acc[5][1]=fmaf(a1.y,wv.y,acc[5][1]);
    acc[5][2]=fmaf(a1.y,wv.z,acc[5][2]); acc[5][3]=fmaf(a1.y,wv.w,acc[5][3]);
    acc[6][0]=fmaf(a1.z,wv.x,acc[6][0]); acc[6][1]=fmaf(a1.z,wv.y,acc[6][1]);
    acc[6][2]=fmaf(a1.z,wv.z,acc[6][2]); acc[6][3]=fmaf(a1.z,wv.w,acc[6][3]);
    acc[7][0]=fmaf(a1.w,wv.x,acc[7][0]); acc[7][1]=fmaf(a1.w,wv.y,acc[7][1]);
    acc[7][2]=fmaf(a1.w,wv.z,acc[7][2]); acc[7][3]=fmaf(a1.w,wv.w,acc[7][3]);
  }
  float* pp = partial + ((size_t)ks*32 + b0)*N + n0;
  #pragma unroll
  for (int bi=0;bi<8;bi++)
    *(float4*)(pp + (size_t)bi*N) =
      make_float4(acc[bi][0],acc[bi][1],acc[bi][2],acc[bi][3]);
}

// ---------------- cell update (reduces 16 K-split partials) -----------------
__global__ __launch_bounds__(256) void k_cell(const float* __restrict__ partial,
    const float* __restrict__ b_ih, const float* __restrict__ b_hh,
    float* __restrict__ c, float* __restrict__ hdst1, float* __restrict__ hdst2){
  int idx = blockIdx.x*256 + threadIdx.x;
  int b = idx >> 10, h = idx & 1023;
  const float* pb = partial + (size_t)b*G4;
  float gi = b_ih[h]      + b_hh[h];
  float gf = b_ih[1024+h] + b_hh[1024+h];
  float gg = b_ih[2048+h] + b_hh[2048+h];
  float go = b_ih[3072+h] + b_hh[3072+h];
  #pragma unroll
  for (int ks=0; ks<16; ks++){
    const float* pp = pb + (size_t)ks*32*G4;
    gi += pp[h]; gf += pp[1024+h]; gg += pp[2048+h]; go += pp[3072+h];
  }
  float cv = c[idx];
  float si = 1.f/(1.f+expf(-gi));
  float sf = 1.f/(1.f+expf(-gf));
  float so = 1.f/(1.f+expf(-go));
  float tg = tanhf(gg);
  float c2 = sf*cv + si*tg;
  float h2 = so*tanhf(c2);
  c[idx] = c2;
  hdst1[h*32 + b] = h2;
  if (hdst2) hdst2[h*32 + b] = h2;
}

// ---------------- combine pred partials + bias, write logits, argmax --------
// grid (125), block 256: n = blk*256+tx in [0,32000)
__global__ __launch_bounds__(256) void k_predsum(const float* __restrict__ partP,
    const float* __restrict__ b_fc, float* __restrict__ outp,
    float* __restrict__ argv, int* __restrict__ argi, int t){
  int n = blockIdx.x*256 + threadIdx.x;
  int w = threadIdx.x >> 6, lane = threadIdx.x & 63;
  float bias = b_fc[n];
  const float* p0 = partP + n;
  const float* p1 = partP + (size_t)32*NPRED + n;
  for (int b=0;b<32;b++){
    float v = p0[(size_t)b*NPRED] + p1[(size_t)b*NPRED] + bias;
    outp[(size_t)(b*TT + t)*VV + n] = v;
    float bv = v; int bi = n;
    #pragma unroll
    for (int d=32; d>0; d>>=1){
      float ov = __shfl_down(bv, d); int oi = __shfl_down(bi, d);
      if (ov > bv || (ov==bv && oi < bi)){ bv=ov; bi=oi; }
    }
    if (lane==0){
      argv[(blockIdx.x*4 + w)*32 + b] = bv;
      argi[(blockIdx.x*4 + w)*32 + b] = bi;
    }
  }
}

// ---------------- final argmax (step 63) ----------------
__global__ void k_argfinal(const float* __restrict__ argv,
                           const int* __restrict__ argi,
                           float* __restrict__ predout){
  int b = threadIdx.x >> 3, j = threadIdx.x & 7;
  float bv = -INFINITY; int bi = 0x7fffffff;
  for (int p=j; p<500; p+=8){
    float v = argv[p*32+b]; int ix = argi[p*32+b];
    if (v>bv || (v==bv && ix<bi)){ bv=v; bi=ix; }
  }
  #pragma unroll
  for (int d=4; d>0; d>>=1){
    float ov = __shfl_down(bv, d); int oi = __shfl_down(bi, d);
    if (ov>bv || (ov==bv && oi<bi)){ bv=ov; bi=oi; }
  }
  if (j==0) predout[b*TT + 63] = (float)bi;
}

extern "C" void kernel_launch(void* const* d_in, const int* in_sizes, int n_in,
                              void* d_out, int out_size, void* d_ws, size_t ws_size,
                              hipStream_t stream){
  const float* enc_output=(const float*)d_in[0];
  const int*   trg       =(const int*)d_in[1];
  const float* emb       =(const float*)d_in[2];
  const float* W_att_enc =(const float*)d_in[3];
  const float* b_att_enc =(const float*)d_in[4];
  const float* W_att_dec =(const float*)d_in[5];
  const float* b_att_dec =(const float*)d_in[6];
  const float* v_att     =(const float*)d_in[7];
  const float* W_in      =(const float*)d_in[8];
  const float* b_in      =(const float*)d_in[9];
  const float* W_ih0     =(const float*)d_in[10];
  const float* W_hh0     =(const float*)d_in[11];
  const float* b_ih0     =(const float*)d_in[12];
  const float* b_hh0     =(const float*)d_in[13];
  const float* W_ih1     =(const float*)d_in[14];
  const float* W_hh1     =(const float*)d_in[15];
  const float* b_ih1     =(const float*)d_in[16];
  const float* b_hh1     =(const float*)d_in[17];
  const float* W_fc      =(const float*)d_in[18];
  const float* b_fc      =(const float*)d_in[19];
  const int*   sosp      =(const int*)d_in[23];

  float* out = (float*)d_out;
  float* predout = out + (size_t)BB*TT*VV;
  float* ws = (float*)d_ws;

  float* WcatPT = ws;                      // [1024][33024]
  float* Wcat0T = ws + 33816576;           // [1536][4096]
  float* Wcat1T = ws + 40108032;           // [2048][4096]
  float* W1T    = ws + 48496640;           // [512][512]
  float* WinCtxT= ws + 48758784;           // [1024][512]
  float* WattET = ws + 49283072;           // [1024][1024]
  float* encT   = ws + 50331648;           // [1024][16384] (precompute only)
  float* partP  = encT;                    // [2][32][33024] reuses encT region
  float* ep     = ws + 67108864;           // [16384][1024]
  float* encW2  = ws + 83886080;           // [16384][512]
  float* part0  = ws + 92274688;           // [16][32][4096]
  float* part1  = ws + 94371840;
  float* A0T    = ws + 96468992;           // [1536][32]  = [x ; h0]
  float* A1T    = ws + 96518144;           // [2048][32]  = [h0 ; h1]
  float* c0     = ws + 96583680;
  float* c1     = ws + 96616448;
  float* q      = ws + 96649216;           // legacy (unused in steps)
  float* scores = ws + 96681984;           // [32][512]
  float* argv   = ws + 96698368;           // [500][32]
  int*   argi   = (int*)(ws + 96714368);   // [500][32]
  int*   token  = (int*)(ws + 96730368);   // [32]

  k_init<<<dim3(4833), dim3(256), 0, stream>>>(out, A0T, A1T, c0, c1, q,
      b_att_dec, token, trg, sosp, predout);

  auto TR=[&](const float* src,int ss,float* dst,int ds,int R,int C){
    k_transpose<<<dim3(C/32, R/32), dim3(32,8), 0, stream>>>(src, ss, dst, ds, R, C);
  };
  TR(W_fc, 1024, WcatPT, NPRED, VV, 1024);
  TR(W_att_dec, 1024, WcatPT + VV, NPRED, 1024, 1024);
  TR(W_ih0, 512, Wcat0T, G4, G4, 512);
  TR(W_hh0, 1024, Wcat0T + (size_t)512*G4, G4, G4, 1024);
  TR(W_ih1, 1024, Wcat1T, G4, G4, 1024);
  TR(W_hh1, 1024, Wcat1T + (size_t)1024*G4, G4, G4, 1024);
  TR(W_in, 1536, W1T, 512, 512, 512);
  TR(W_in + 512, 1536, WinCtxT, 512, 512, 1024);
  TR(W_att_enc, 1024, WattET, 1024, 1024, 1024);
  TR(enc_output, 1024, encT, 16384, 16384, 1024);

  k_pregemm<<<dim3(256,8), dim3(256), 0, stream>>>(encT, WattET, b_att_enc, ep, 1024, 1024);
  k_pregemm<<<dim3(256,4), dim3(256), 0, stream>>>(encT, WinCtxT, nullptr, encW2, 512, 1024);

  for (int t=1; t<TT; t++){
    k_score<<<dim3(32,16), dim3(256), 0, stream>>>(ep, partP, b_att_dec, v_att,
        scores, argv, argi, token, predout, t);
    k_attnx<<<dim3(32,8), dim3(256), 0, stream>>>(scores, encW2, emb, token,
        W1T, b_in, A0T);
    k_gemm_smallM<<<dim3(16,16), dim3(256), 0, stream>>>(A0T, Wcat0T, part0,
        G4, 96);
    k_cell<<<dim3(128), dim3(256), 0, stream>>>(part0, b_ih0, b_hh0, c0,
        A0T + (size_t)512*32, A1T);
    k_gemm_smallM<<<dim3(16,16), dim3(256), 0, stream>>>(A1T, Wcat1T, part1,
        G4, 128);
    k_cell<<<dim3(128), dim3(256), 0, stream>>>(part1, b_ih1, b_hh1, c1,
        A1T + (size_t)1024*32, nullptr);
    k_gemm_smallM<<<dim3(129,2), dim3(256), 0, stream>>>(A1T + (size_t)1024*32,
        WcatPT, partP, NPRED, 512);
    k_predsum<<<dim3(125), dim3(256), 0, stream>>>(partP, b_fc, out, argv, argi, t);
  }
  k_argfinal<<<dim3(1), dim3(256), 0, stream>>>(argv, argi, predout);
}